// Round 4
// baseline (8437.950 us; speedup 1.0000x reference)
//
#include <hip/hip_runtime.h>
#include <hip/hip_bf16.h>

// Problem constants
#define BB 32
#define SS 512
#define DD 256
#define HH 256
#define GG 1024          // 4*H
#define MM (SS*BB)       // 16384 rows, m = s*32 + b
#define NSENT 16
#define TT 12
#define TAG_START 10
#define TAG_STOP 11

typedef unsigned long long u64;
typedef unsigned int u32;

__device__ __forceinline__ float sigm(float x) {
  x = fminf(fmaxf(x, -15.f), 15.f);
  return 1.f / (1.f + __expf(-x));
}
__device__ __forceinline__ float tanh_fast(float x) {
  x = fminf(fmaxf(x, -15.f), 15.f);
  float e = __expf(2.f * x);
  return (e - 1.f) / (e + 1.f);
}

// ---------------- embed gather: X1[m][d] = embed[inputs[b][s]][d], m = s*32+b
__global__ void embed_kernel(const int* __restrict__ toks, const float* __restrict__ emb,
                             float* __restrict__ X1) {
  int m = blockIdx.x;
  int s = m >> 5, b = m & 31;
  int tok = toks[b * SS + s];
  ((float4*)(X1 + (size_t)m * DD))[threadIdx.x] =
      ((const float4*)(emb + (size_t)tok * DD))[threadIdx.x];
}

// ---------------- fp32 NT GEMM (R9-verified core + z-batching):
// C[M,N] = A[M,K](lda) @ W[N,K](ldw)^T + bias.  128x128 tile, 8x8/thread.
// blockIdx.z selects direction: W += z*wz, C += z*cz, bias += z*GG.
__launch_bounds__(256)
__global__ void gemm_nt(const float* __restrict__ A, const float* __restrict__ W_,
                        const float* __restrict__ bias_, float* __restrict__ C_,
                        int K, int lda, int ldw, int ldC, size_t wz, size_t cz) {
  __shared__ float As[16 * 132];
  __shared__ float Ws[16 * 132];
  const float* W = W_ + (size_t)blockIdx.z * wz;
  const float* bias = bias_ ? bias_ + (size_t)blockIdx.z * GG : nullptr;
  float* C = C_ + (size_t)blockIdx.z * cz;
  const int tid = threadIdx.x;
  const int n0 = blockIdx.x * 128, m0 = blockIdx.y * 128;
  const int row = tid & 127, half = tid >> 7;    // staging: 128 rows x 2 k-halves
  const int tx = tid & 15, ty = tid >> 4;        // compute: 16x16 thread grid
  float acc[8][8] = {};
  const float* Arow = A + (size_t)(m0 + row) * lda;
  const float* Wrow = W + (size_t)(n0 + row) * ldw;
  for (int kk = 0; kk < K; kk += 16) {
    const int kb = half * 8;
    float4 a0 = *(const float4*)(Arow + kk + kb);
    float4 a1 = *(const float4*)(Arow + kk + kb + 4);
    float4 w0 = *(const float4*)(Wrow + kk + kb);
    float4 w1 = *(const float4*)(Wrow + kk + kb + 4);
    As[(kb + 0) * 132 + row] = a0.x; As[(kb + 1) * 132 + row] = a0.y;
    As[(kb + 2) * 132 + row] = a0.z; As[(kb + 3) * 132 + row] = a0.w;
    As[(kb + 4) * 132 + row] = a1.x; As[(kb + 5) * 132 + row] = a1.y;
    As[(kb + 6) * 132 + row] = a1.z; As[(kb + 7) * 132 + row] = a1.w;
    Ws[(kb + 0) * 132 + row] = w0.x; Ws[(kb + 1) * 132 + row] = w0.y;
    Ws[(kb + 2) * 132 + row] = w0.z; Ws[(kb + 3) * 132 + row] = w0.w;
    Ws[(kb + 4) * 132 + row] = w1.x; Ws[(kb + 5) * 132 + row] = w1.y;
    Ws[(kb + 6) * 132 + row] = w1.z; Ws[(kb + 7) * 132 + row] = w1.w;
    __syncthreads();
#pragma unroll
    for (int kl = 0; kl < 16; ++kl) {
      const float4 alo = *(const float4*)&As[kl * 132 + ty * 4];
      const float4 ahi = *(const float4*)&As[kl * 132 + 64 + ty * 4];
      const float4 wlo = *(const float4*)&Ws[kl * 132 + tx * 4];
      const float4 whi = *(const float4*)&Ws[kl * 132 + 64 + tx * 4];
      const float am[8] = {alo.x, alo.y, alo.z, alo.w, ahi.x, ahi.y, ahi.z, ahi.w};
      const float wm[8] = {wlo.x, wlo.y, wlo.z, wlo.w, whi.x, whi.y, whi.z, whi.w};
#pragma unroll
      for (int i = 0; i < 8; ++i)
#pragma unroll
        for (int j = 0; j < 8; ++j) acc[i][j] = fmaf(am[i], wm[j], acc[i][j]);
    }
    __syncthreads();
  }
  float4 blo = make_float4(0.f, 0.f, 0.f, 0.f), bhi = blo;
  if (bias) {
    blo = *(const float4*)(bias + n0 + tx * 4);
    bhi = *(const float4*)(bias + n0 + 64 + tx * 4);
  }
#pragma unroll
  for (int i = 0; i < 8; ++i) {
    const int m = m0 + ((i < 4) ? (ty * 4 + i) : (64 + ty * 4 + i - 4));
    float4 lo = make_float4(acc[i][0] + blo.x, acc[i][1] + blo.y,
                            acc[i][2] + blo.z, acc[i][3] + blo.w);
    float4 hi = make_float4(acc[i][4] + bhi.x, acc[i][5] + bhi.y,
                            acc[i][6] + bhi.z, acc[i][7] + bhi.w);
    *(float4*)(C + (size_t)m * ldC + n0 + tx * 4) = lo;
    *(float4*)(C + (size_t)m * ldC + n0 + 64 + tx * 4) = hi;
  }
}

// ---------------- whh repack (unchanged layout): [d][sl][i4(32)][t(256)][4],
// t = half*128 + r; value = whh[d][gcol(r,sl)][half*128 + i4*4 + c].
__global__ void prep_whh(const float* __restrict__ whh1, const float* __restrict__ whh2,
                         float* __restrict__ o1, float* __restrict__ o2) {
  int idx0 = blockIdx.x * 256 + threadIdx.x;       // 2 * 524288
  int layer = idx0 >> 19;
  int idx = idx0 & 524287;
  const float* whh = layer ? whh2 : whh1;
  float* out = layer ? o2 : o1;
  int c    = idx & 3;
  int t    = (idx >> 2) & 255;
  int i4   = (idx >> 10) & 31;
  int sl   = (idx >> 15) & 7;
  int d    = idx >> 18;
  int r    = t & 127;
  int half = t >> 7;
  int g = (r >> 5) * 256 + sl * 32 + (r & 31);
  int k = half * 128 + i4 * 4 + c;
  out[idx] = whh[(size_t)(d * GG + g) * HH + k];
}

// ---------------- attadd: Xp[d][m][g] += sum_n aw[m][n] * sentW[d][(m&31)*16+n][g]
// (rank-16 attention term folded out of rec2's per-step critical path)
__global__ void attadd_kernel(const float* __restrict__ aw, const float* __restrict__ sentW,
                              float* __restrict__ Xp) {
  __shared__ float a[NSENT];
  const int idx = blockIdx.x;          // d*MM + m
  const int d = idx >> 14;             // MM = 16384 = 2^14
  const int m = idx & (MM - 1);
  const int b = m & 31;
  const int tid = threadIdx.x;
  if (tid < NSENT) a[tid] = aw[(size_t)m * 16 + tid];
  __syncthreads();
  const int g = tid * 4;
  float* xp = Xp + ((size_t)d * MM + m) * GG + g;
  const float* swp = sentW + ((size_t)d * 512 + b * 16) * 1024 + g;
  float4 acc = *(const float4*)xp;
#pragma unroll
  for (int n = 0; n < NSENT; ++n) {
    const float4 sw = *(const float4*)&swp[(size_t)n * 1024];
    acc.x = fmaf(a[n], sw.x, acc.x);
    acc.y = fmaf(a[n], sw.y, acc.y);
    acc.z = fmaf(a[n], sw.z, acc.z);
    acc.w = fmaf(a[n], sw.w, acc.w);
  }
  *(float4*)xp = acc;
}

// ---------------- LSTM recurrence. Protocol (tags, slot ping-pong, word map,
// producer 8B agent atomic) IDENTICAL to verified version. Changes this round:
//  - 4 batch cols per chain group -> 128 wgs (halves global poll/store traffic)
//  - ONLY wave0 polls; each lane owns 16 words = 2 whole 64B lines ->
//    one poll stream per line (16x fewer streams; was 4 pollers/line x 65536)
//  - raw s_barrier + lgkmcnt(0) + sched_barrier(0) instead of __syncthreads:
//    outstanding global loads/stores are NOT drained at barriers (vmcnt is
//    per-wave), removing the per-step HBM stall
//  - xp loads software-pipelined one step ahead (issued post-detect)
//  - attention removed (folded into Xp by attadd_kernel)
__launch_bounds__(256, 1)
__global__ void rec_kernel(const float* __restrict__ Xp, const float* __restrict__ whh_p,
                           float* __restrict__ hist, u64* __restrict__ hx) {
  __shared__ float h_lds[1024];      // [c*256 + k], c = 0..3
  __shared__ float p_lds[1024];      // [(half*128 + r)*4 + c]
  const int tid = threadIdx.x;
  const int bid = blockIdx.x;        // 128 wgs: sl(8) x d(2) x bq(8)
  const int sl = bid >> 4;
  const int db = bid & 15;
  const int d = db & 1;
  const int bq = db >> 1;            // batch quad: cols bq*4 .. bq*4+3
  const int r = tid & 127;
  const int half = tid >> 7;
  // -------- register-resident whh half-row (w[128]/thread; 164-200 VGPR, no spill)
  const float* wp = whh_p + (size_t)(d * 8 + sl) * 32768;
  float w[128];
#pragma unroll
  for (int i4 = 0; i4 < 32; ++i4) {
    const float4 v = *(const float4*)&wp[(size_t)(i4 * 256 + tid) * 4];
    w[i4 * 4 + 0] = v.x; w[i4 * 4 + 1] = v.y;
    w[i4 * 4 + 2] = v.z; w[i4 * 4 + 3] = v.w;
  }
  const float* XpD = Xp + (size_t)d * MM * GG;
  const int gcol = (r >> 5) * 256 + sl * 32 + (r & 31);
  const int etid = tid - 128;        // epilogue on waves 2,3 (frees wave0 to spin)
  const int ecc = (etid >= 0) ? (etid >> 5) : 0;
  const int ejj = etid & 31;
  float creg = 0.f;                  // LSTM cell state (valid etid>=0)
  // group base: hx[slot][d][bq][1024]
  u64* grp[2] = { hx + ((size_t)(0 * 2 + d) * 8 + bq) * 1024,
                  hx + ((size_t)(1 * 2 + d) * 8 + bq) * 1024 };
  // xp prefetch registers (half==0 threads own the xp add), one step ahead
  float xn0 = 0.f, xn1 = 0.f, xn2 = 0.f, xn3 = 0.f;
  {
    const int s0 = d ? (SS - 1) : 0;
    const int m0 = s0 * BB + bq * 4;
    if (half == 0) {
      xn0 = XpD[(size_t)(m0 + 0) * GG + gcol];
      xn1 = XpD[(size_t)(m0 + 1) * GG + gcol];
      xn2 = XpD[(size_t)(m0 + 2) * GG + gcol];
      xn3 = XpD[(size_t)(m0 + 3) * GG + gcol];
    }
  }
#pragma unroll 1
  for (int t = 0; t < SS; ++t) {
    const float xc0 = xn0, xc1 = xn1, xc2 = xn2, xc3 = xn3;
    const int tn = (t + 1 < SS) ? (t + 1) : (SS - 1);
    const int sn = d ? (SS - 1 - tn) : tn;
    const int m0n = sn * BB + bq * 4;
    if (tid < 64) {
      // ---- wave0: poll all 1024 words, 16/lane (2 whole lines per lane) ----
      u64 pw[16];
      u64* base = grp[t & 1] + tid * 16;
      for (;;) {
#pragma unroll
        for (int q = 0; q < 16; ++q)
          pw[q] = __hip_atomic_load(base + q, __ATOMIC_RELAXED, __HIP_MEMORY_SCOPE_AGENT);
        bool ok = true;
#pragma unroll
        for (int q = 0; q < 16; ++q) ok &= ((u32)(pw[q] >> 32) == (u32)t);
        if (__all(ok)) break;
        __builtin_amdgcn_s_sleep(1);
      }
      // h -> LDS (from regs), then hist (bulk coalesced, from regs)
      float4 hv0 = make_float4(__uint_as_float((u32)pw[0]),  __uint_as_float((u32)pw[1]),
                               __uint_as_float((u32)pw[2]),  __uint_as_float((u32)pw[3]));
      float4 hv1 = make_float4(__uint_as_float((u32)pw[4]),  __uint_as_float((u32)pw[5]),
                               __uint_as_float((u32)pw[6]),  __uint_as_float((u32)pw[7]));
      float4 hv2 = make_float4(__uint_as_float((u32)pw[8]),  __uint_as_float((u32)pw[9]),
                               __uint_as_float((u32)pw[10]), __uint_as_float((u32)pw[11]));
      float4 hv3 = make_float4(__uint_as_float((u32)pw[12]), __uint_as_float((u32)pw[13]),
                               __uint_as_float((u32)pw[14]), __uint_as_float((u32)pw[15]));
      *(float4*)&h_lds[tid * 16 + 0]  = hv0;
      *(float4*)&h_lds[tid * 16 + 4]  = hv1;
      *(float4*)&h_lds[tid * 16 + 8]  = hv2;
      *(float4*)&h_lds[tid * 16 + 12] = hv3;
      if (t > 0) {
        const int sp = d ? (SS - t) : (t - 1);
        const int c = tid >> 4, k0 = (tid & 15) * 16;
        float* hp = &hist[(size_t)(sp * BB + bq * 4 + c) * 512 + d * 256 + k0];
        *(float4*)&hp[0]  = hv0;
        *(float4*)&hp[4]  = hv1;
        *(float4*)&hp[8]  = hv2;
        *(float4*)&hp[12] = hv3;
      }
      // xp prefetch for t+1 (wave0 is half 0) — fire and forget
      xn0 = XpD[(size_t)(m0n + 0) * GG + gcol];
      xn1 = XpD[(size_t)(m0n + 1) * GG + gcol];
      xn2 = XpD[(size_t)(m0n + 2) * GG + gcol];
      xn3 = XpD[(size_t)(m0n + 3) * GG + gcol];
    } else if (half == 0) {
      // wave1: xp prefetch for t+1 (per-wave vmcnt: never blocks wave0's spin)
      xn0 = XpD[(size_t)(m0n + 0) * GG + gcol];
      xn1 = XpD[(size_t)(m0n + 1) * GG + gcol];
      xn2 = XpD[(size_t)(m0n + 2) * GG + gcol];
      xn3 = XpD[(size_t)(m0n + 3) * GG + gcol];
    }
    // ---- barrier (b): h_lds ready. Raw barrier: globals stay in flight. ----
    asm volatile("s_waitcnt lgkmcnt(0)" ::: "memory");
    __builtin_amdgcn_s_barrier();
    __builtin_amdgcn_sched_barrier(0);
    {
      // matvec: 4 cols, 8 independent accumulator chains; w from regs,
      // h via wave-uniform (broadcast, conflict-free) LDS reads
      const int kb = half * 128;
      float p0a = 0.f, p0b = 0.f, p1a = 0.f, p1b = 0.f;
      float p2a = 0.f, p2b = 0.f, p3a = 0.f, p3b = 0.f;
#pragma unroll
      for (int k8 = 0; k8 < 16; ++k8) {
        const float4 hA0 = *(const float4*)&h_lds[kb + k8 * 8];
        const float4 hB0 = *(const float4*)&h_lds[kb + k8 * 8 + 4];
        const float4 hA1 = *(const float4*)&h_lds[256 + kb + k8 * 8];
        const float4 hB1 = *(const float4*)&h_lds[256 + kb + k8 * 8 + 4];
        const float4 hA2 = *(const float4*)&h_lds[512 + kb + k8 * 8];
        const float4 hB2 = *(const float4*)&h_lds[512 + kb + k8 * 8 + 4];
        const float4 hA3 = *(const float4*)&h_lds[768 + kb + k8 * 8];
        const float4 hB3 = *(const float4*)&h_lds[768 + kb + k8 * 8 + 4];
        p0a = fmaf(w[k8*8+0], hA0.x, p0a); p0a = fmaf(w[k8*8+1], hA0.y, p0a);
        p0a = fmaf(w[k8*8+2], hA0.z, p0a); p0a = fmaf(w[k8*8+3], hA0.w, p0a);
        p0b = fmaf(w[k8*8+4], hB0.x, p0b); p0b = fmaf(w[k8*8+5], hB0.y, p0b);
        p0b = fmaf(w[k8*8+6], hB0.z, p0b); p0b = fmaf(w[k8*8+7], hB0.w, p0b);
        p1a = fmaf(w[k8*8+0], hA1.x, p1a); p1a = fmaf(w[k8*8+1], hA1.y, p1a);
        p1a = fmaf(w[k8*8+2], hA1.z, p1a); p1a = fmaf(w[k8*8+3], hA1.w, p1a);
        p1b = fmaf(w[k8*8+4], hB1.x, p1b); p1b = fmaf(w[k8*8+5], hB1.y, p1b);
        p1b = fmaf(w[k8*8+6], hB1.z, p1b); p1b = fmaf(w[k8*8+7], hB1.w, p1b);
        p2a = fmaf(w[k8*8+0], hA2.x, p2a); p2a = fmaf(w[k8*8+1], hA2.y, p2a);
        p2a = fmaf(w[k8*8+2], hA2.z, p2a); p2a = fmaf(w[k8*8+3], hA2.w, p2a);
        p2b = fmaf(w[k8*8+4], hB2.x, p2b); p2b = fmaf(w[k8*8+5], hB2.y, p2b);
        p2b = fmaf(w[k8*8+6], hB2.z, p2b); p2b = fmaf(w[k8*8+7], hB2.w, p2b);
        p3a = fmaf(w[k8*8+0], hA3.x, p3a); p3a = fmaf(w[k8*8+1], hA3.y, p3a);
        p3a = fmaf(w[k8*8+2], hA3.z, p3a); p3a = fmaf(w[k8*8+3], hA3.w, p3a);
        p3b = fmaf(w[k8*8+4], hB3.x, p3b); p3b = fmaf(w[k8*8+5], hB3.y, p3b);
        p3b = fmaf(w[k8*8+6], hB3.z, p3b); p3b = fmaf(w[k8*8+7], hB3.w, p3b);
      }
      *(float4*)&p_lds[tid * 4] = make_float4(p0a + p0b + xc0, p1a + p1b + xc1,
                                              p2a + p2b + xc2, p3a + p3b + xc3);
    }
    // ---- barrier (c): p_lds ready; also fences h_lds reads vs next write ----
    asm volatile("s_waitcnt lgkmcnt(0)" ::: "memory");
    __builtin_amdgcn_s_barrier();
    __builtin_amdgcn_sched_barrier(0);
    if (etid >= 0) {   // producer epilogue on waves 2,3: one 8B L3 atomic each
      const float iv = p_lds[(ejj) * 4 + ecc]      + p_lds[(128 + ejj) * 4 + ecc];
      const float fv = p_lds[(32 + ejj) * 4 + ecc] + p_lds[(160 + ejj) * 4 + ecc];
      const float gv = p_lds[(64 + ejj) * 4 + ecc] + p_lds[(192 + ejj) * 4 + ecc];
      const float ov = p_lds[(96 + ejj) * 4 + ecc] + p_lds[(224 + ejj) * 4 + ecc];
      const float cs = sigm(fv) * creg + sigm(iv) * tanh_fast(gv);
      creg = cs;
      const float hn = sigm(ov) * tanh_fast(cs);
      u64 wv = ((u64)(u32)(t + 1) << 32) | (u64)__float_as_uint(hn);
      __hip_atomic_store(grp[(t + 1) & 1] + ecc * 256 + sl * 32 + ejj, wv,
                         __ATOMIC_RELAXED, __HIP_MEMORY_SCOPE_AGENT);
    }
  }
  // final flush (tag SS): wave0 polls its own 16 words, writes last hist row
  if (tid < 64) {
    u64 pw[16];
    u64* base = grp[SS & 1] + tid * 16;
    for (;;) {
#pragma unroll
      for (int q = 0; q < 16; ++q)
        pw[q] = __hip_atomic_load(base + q, __ATOMIC_RELAXED, __HIP_MEMORY_SCOPE_AGENT);
      bool ok = true;
#pragma unroll
      for (int q = 0; q < 16; ++q) ok &= ((u32)(pw[q] >> 32) == (u32)SS);
      if (__all(ok)) break;
      __builtin_amdgcn_s_sleep(1);
    }
    const int sp = d ? 0 : (SS - 1);
    const int c = tid >> 4, k0 = (tid & 15) * 16;
    float* hp = &hist[(size_t)(sp * BB + bq * 4 + c) * 512 + d * 256 + k0];
#pragma unroll
    for (int q = 0; q < 16; q += 4)
      *(float4*)&hp[q] = make_float4(__uint_as_float((u32)pw[q]),
                                     __uint_as_float((u32)pw[q + 1]),
                                     __uint_as_float((u32)pw[q + 2]),
                                     __uint_as_float((u32)pw[q + 3]));
  }
}

// ---------------- aw: scores over NS=16 sentence embs + softmax -> aw[m][16]
__global__ void aw_kernel(const float* __restrict__ wx, const float* __restrict__ sent,
                          float* __restrict__ awout) {
  __shared__ float sl[NSENT * 512];   // 32 KB
  __shared__ float wxr[512];
  __shared__ float parts[256];
  __shared__ float avals[NSENT];
  __shared__ float red0;
  const int tid = threadIdx.x;
  const int b = blockIdx.y;
  const int s0 = blockIdx.x * 32;
  for (int i = tid; i < NSENT * 512; i += 256) sl[i] = sent[(size_t)b * NSENT * 512 + i];
  __syncthreads();
  for (int si = 0; si < 32; ++si) {
    const int m = (s0 + si) * BB + b;
    for (int i = tid; i < 512; i += 256) wxr[i] = wx[(size_t)m * 512 + i];
    __syncthreads();
    const int n = tid >> 4, kp = tid & 15;
    float p = 0.f;
#pragma unroll 8
    for (int f = kp * 32; f < kp * 32 + 32; ++f) p = fmaf(wxr[f], sl[n * 512 + f], p);
    parts[tid] = p;
    __syncthreads();
    if (tid < NSENT) {
      float sc = 0.f;
      for (int qq = 0; qq < 16; ++qq) sc += parts[tid * 16 + qq];
      avals[tid] = sc;
    }
    __syncthreads();
    if (tid == 0) {
      float mx = avals[0];
      for (int qq = 1; qq < NSENT; ++qq) mx = fmaxf(mx, avals[qq]);
      float sm = 0.f;
      for (int qq = 0; qq < NSENT; ++qq) { float e = expf(avals[qq] - mx); avals[qq] = e; sm += e; }
      red0 = 1.f / sm;
    }
    __syncthreads();
    if (tid < NSENT) awout[(size_t)m * 16 + tid] = avals[tid] * red0;
    __syncthreads();
  }
}

// ---------------- feats[m][t] = l2m[m][:] . h2t_w[t][:] + h2t_b[t]; wave per row
__global__ void feats_kernel(const float* __restrict__ l2m, const float* __restrict__ w,
                             const float* __restrict__ bias, float* __restrict__ feats) {
  const int wave = threadIdx.x >> 6, lane = threadIdx.x & 63;
  const int m = blockIdx.x * 4 + wave;
  const float* row = l2m + (size_t)m * 512;
  float rv[8];
#pragma unroll
  for (int i = 0; i < 8; ++i) rv[i] = row[lane + i * 64];
  for (int t = 0; t < TT; ++t) {
    const float* wr = w + t * 512;
    float p = 0.f;
#pragma unroll
    for (int i = 0; i < 8; ++i) p = fmaf(rv[i], wr[lane + i * 64], p);
#pragma unroll
    for (int off = 32; off; off >>= 1) p += __shfl_down(p, off);
    if (lane == 0) feats[(size_t)m * TT + t] = p + bias[t];
  }
}

// ---------------- viterbi per batch; 1 wave, whole DP in LDS
__global__ void viterbi_kernel(const float* __restrict__ feats, const float* __restrict__ trans,
                               int* __restrict__ out) {
  __shared__ float flds[SS * TT];
  __shared__ unsigned char bp[SS * TT];
  __shared__ float tr[TT * TT];
  __shared__ float fv[TT];
  __shared__ float tv[TT];
  __shared__ int pathS[SS];
  const int b = blockIdx.x, tid = threadIdx.x;
  for (int i = tid; i < SS * TT; i += 64) {
    int s = i / TT, t = i - s * TT;
    flds[i] = feats[(size_t)(s * BB + b) * TT + t];
  }
  for (int i = tid; i < TT * TT; i += 64) tr[i] = trans[i];
  if (tid < TT) fv[tid] = (tid == TAG_START) ? 0.f : -10000.f;
  __syncthreads();
  for (int s = 0; s < SS; ++s) {
    float nf = 0.f;
    if (tid < TT) {
      float mx = -1e30f;
      int bj = 0;
#pragma unroll
      for (int jj = 0; jj < TT; ++jj) {
        float v = fv[jj] + tr[tid * TT + jj];
        if (v > mx) { mx = v; bj = jj; }
      }
      nf = mx + flds[s * TT + tid];
      bp[s * TT + tid] = (unsigned char)bj;
    }
    __syncthreads();
    if (tid < TT) fv[tid] = nf;
    __syncthreads();
  }
  if (tid < TT) tv[tid] = fv[tid] + tr[TAG_STOP * TT + tid];
  __syncthreads();
  if (tid == 0) {
    int best = 0;
    float mx = tv[0];
    for (int jj = 1; jj < TT; ++jj)
      if (tv[jj] > mx) { mx = tv[jj]; best = jj; }
    pathS[SS - 1] = best;
    for (int s = SS - 1; s > 0; --s) { best = bp[s * TT + best]; pathS[s - 1] = best; }
  }
  __syncthreads();
  for (int s = tid; s < SS; s += 64) out[b * SS + s] = pathS[s];
}

// ---------------- workspace layout (bytes) — total ~245.6 MB < 256 MB ----------------
#define OFF_XP    ((size_t)0)               // 2*16384*1024*4 = 134217728
#define OFF_WX    ((size_t)134217728)       // 16384*512*4 = 33554432
#define OFF_L2M   ((size_t)167772160)       // 16384*512*4 = 33554432 (X1 aliases here)
#define OFF_WORD  ((size_t)201326592)       // 16384*512*4 = 33554432
#define OFF_WT1   ((size_t)234881024)       // 2097152
#define OFF_WT2   ((size_t)236978176)       // 2097152
#define OFF_FEATS ((size_t)239075328)       // 786432
#define OFF_HX1   ((size_t)239861760)       // 262144
#define OFF_HX2   ((size_t)240123904)       // 262144
#define OFF_SENTW ((size_t)240386048)       // 2*512*1024*4 = 4194304
#define OFF_AW    ((size_t)244580352)       // 16384*16*4 = 1048576

extern "C" void kernel_launch(void* const* d_in, const int* in_sizes, int n_in,
                              void* d_out, int out_size, void* d_ws, size_t ws_size,
                              hipStream_t stream) {
  const int* inputs  = (const int*)d_in[0];
  const float* sent  = (const float*)d_in[1];
  const float* emb   = (const float*)d_in[2];
  const float* l1wih = (const float*)d_in[3];
  const float* l1whh = (const float*)d_in[4];
  const float* l1b   = (const float*)d_in[5];
  const float* l2wih = (const float*)d_in[6];
  const float* l2whh = (const float*)d_in[7];
  const float* l2b   = (const float*)d_in[8];
  const float* attW  = (const float*)d_in[9];
  const float* h2tw  = (const float*)d_in[10];
  const float* h2tb  = (const float*)d_in[11];
  const float* trans = (const float*)d_in[12];
  int* out = (int*)d_out;
  char* ws = (char*)d_ws;

  float* Xp    = (float*)(ws + OFF_XP);
  float* wx    = (float*)(ws + OFF_WX);
  float* l2m   = (float*)(ws + OFF_L2M);
  float* X1    = l2m;    // X1 dead (read only by l1 gemms) before rec2 writes l2m
  float* word  = (float*)(ws + OFF_WORD);
  float* wt1   = (float*)(ws + OFF_WT1);
  float* wt2   = (float*)(ws + OFF_WT2);
  float* feats = (float*)(ws + OFF_FEATS);
  u64* hx1     = (u64*)(ws + OFF_HX1);
  u64* hx2     = (u64*)(ws + OFF_HX2);
  float* sentW = (float*)(ws + OFF_SENTW);
  float* awb   = (float*)(ws + OFF_AW);

  // zero both tagged-h buffers (contiguous 512 KB): tag 0 == "h_{-1}=0 ready"
  (void)hipMemsetAsync(ws + OFF_HX1, 0, 262144 * 2, stream);

  prep_whh<<<4096, 256, 0, stream>>>(l1whh, l2whh, wt1, wt2);
  // sentW[d][b*16+n][g] = sent[b][n][:512] . l2wih[d][g][512:1024]
  gemm_nt<<<dim3(8, 4, 2), 256, 0, stream>>>(sent, l2wih + 512, nullptr, sentW,
                                             512, 512, GG, 1024,
                                             (size_t)GG * GG, (size_t)512 * 1024);
  embed_kernel<<<MM, 64, 0, stream>>>(inputs, emb, X1);
  gemm_nt<<<dim3(8, 128, 2), 256, 0, stream>>>(X1, l1wih, l1b, Xp,
                                               DD, DD, DD, GG,
                                               (size_t)GG * DD, (size_t)MM * GG);
  rec_kernel<<<128, 256, 0, stream>>>(Xp, wt1, word, hx1);
  // wx = word @ attW^T
  gemm_nt<<<dim3(4, 128, 1), 256, 0, stream>>>(word, attW, nullptr, wx,
                                               512, 512, 512, 512, 0, 0);
  aw_kernel<<<dim3(16, 32), 256, 0, stream>>>(wx, sent, awb);
  // Xp2 = wx @ l2wih[:, :512]^T + bias
  gemm_nt<<<dim3(8, 128, 2), 256, 0, stream>>>(wx, l2wih, l2b, Xp,
                                               512, 512, GG, GG,
                                               (size_t)GG * GG, (size_t)MM * GG);
  // fold rank-16 attention term into Xp (off rec2's critical path)
  attadd_kernel<<<2 * MM, 256, 0, stream>>>(awb, sentW, Xp);
  rec_kernel<<<128, 256, 0, stream>>>(Xp, wt2, l2m, hx2);
  feats_kernel<<<MM / 4, 256, 0, stream>>>(l2m, h2tw, h2tb, feats);
  viterbi_kernel<<<BB, 64, 0, stream>>>(feats, trans, out);
}

// Round 5
// 6978.162 us; speedup vs baseline: 1.2092x; 1.2092x over previous
//
#include <hip/hip_runtime.h>
#include <hip/hip_bf16.h>

// Problem constants
#define BB 32
#define SS 512
#define DD 256
#define HH 256
#define GG 1024          // 4*H
#define MM (SS*BB)       // 16384 rows, m = s*32 + b
#define NSENT 16
#define TT 12
#define TAG_START 10
#define TAG_STOP 11

typedef unsigned long long u64;
typedef unsigned int u32;

__device__ __forceinline__ float sigm(float x) {
  x = fminf(fmaxf(x, -15.f), 15.f);
  return 1.f / (1.f + __expf(-x));
}
__device__ __forceinline__ float tanh_fast(float x) {
  x = fminf(fmaxf(x, -15.f), 15.f);
  float e = __expf(2.f * x);
  return (e - 1.f) / (e + 1.f);
}

// ---------------- embed gather: X1[m][d] = embed[inputs[b][s]][d], m = s*32+b
__global__ void embed_kernel(const int* __restrict__ toks, const float* __restrict__ emb,
                             float* __restrict__ X1) {
  int m = blockIdx.x;
  int s = m >> 5, b = m & 31;
  int tok = toks[b * SS + s];
  ((float4*)(X1 + (size_t)m * DD))[threadIdx.x] =
      ((const float4*)(emb + (size_t)tok * DD))[threadIdx.x];
}

// ---------------- fp32 NT GEMM (R9-verified core + z-batching):
// C[M,N] = A[M,K](lda) @ W[N,K](ldw)^T + bias.  128x128 tile, 8x8/thread.
// blockIdx.z selects direction: W += z*wz, C += z*cz, bias += z*GG.
__launch_bounds__(256)
__global__ void gemm_nt(const float* __restrict__ A, const float* __restrict__ W_,
                        const float* __restrict__ bias_, float* __restrict__ C_,
                        int K, int lda, int ldw, int ldC, size_t wz, size_t cz) {
  __shared__ float As[16 * 132];
  __shared__ float Ws[16 * 132];
  const float* W = W_ + (size_t)blockIdx.z * wz;
  const float* bias = bias_ ? bias_ + (size_t)blockIdx.z * GG : nullptr;
  float* C = C_ + (size_t)blockIdx.z * cz;
  const int tid = threadIdx.x;
  const int n0 = blockIdx.x * 128, m0 = blockIdx.y * 128;
  const int row = tid & 127, half = tid >> 7;    // staging: 128 rows x 2 k-halves
  const int tx = tid & 15, ty = tid >> 4;        // compute: 16x16 thread grid
  float acc[8][8] = {};
  const float* Arow = A + (size_t)(m0 + row) * lda;
  const float* Wrow = W + (size_t)(n0 + row) * ldw;
  for (int kk = 0; kk < K; kk += 16) {
    const int kb = half * 8;
    float4 a0 = *(const float4*)(Arow + kk + kb);
    float4 a1 = *(const float4*)(Arow + kk + kb + 4);
    float4 w0 = *(const float4*)(Wrow + kk + kb);
    float4 w1 = *(const float4*)(Wrow + kk + kb + 4);
    As[(kb + 0) * 132 + row] = a0.x; As[(kb + 1) * 132 + row] = a0.y;
    As[(kb + 2) * 132 + row] = a0.z; As[(kb + 3) * 132 + row] = a0.w;
    As[(kb + 4) * 132 + row] = a1.x; As[(kb + 5) * 132 + row] = a1.y;
    As[(kb + 6) * 132 + row] = a1.z; As[(kb + 7) * 132 + row] = a1.w;
    Ws[(kb + 0) * 132 + row] = w0.x; Ws[(kb + 1) * 132 + row] = w0.y;
    Ws[(kb + 2) * 132 + row] = w0.z; Ws[(kb + 3) * 132 + row] = w0.w;
    Ws[(kb + 4) * 132 + row] = w1.x; Ws[(kb + 5) * 132 + row] = w1.y;
    Ws[(kb + 6) * 132 + row] = w1.z; Ws[(kb + 7) * 132 + row] = w1.w;
    __syncthreads();
#pragma unroll
    for (int kl = 0; kl < 16; ++kl) {
      const float4 alo = *(const float4*)&As[kl * 132 + ty * 4];
      const float4 ahi = *(const float4*)&As[kl * 132 + 64 + ty * 4];
      const float4 wlo = *(const float4*)&Ws[kl * 132 + tx * 4];
      const float4 whi = *(const float4*)&Ws[kl * 132 + 64 + tx * 4];
      const float am[8] = {alo.x, alo.y, alo.z, alo.w, ahi.x, ahi.y, ahi.z, ahi.w};
      const float wm[8] = {wlo.x, wlo.y, wlo.z, wlo.w, whi.x, whi.y, whi.z, whi.w};
#pragma unroll
      for (int i = 0; i < 8; ++i)
#pragma unroll
        for (int j = 0; j < 8; ++j) acc[i][j] = fmaf(am[i], wm[j], acc[i][j]);
    }
    __syncthreads();
  }
  float4 blo = make_float4(0.f, 0.f, 0.f, 0.f), bhi = blo;
  if (bias) {
    blo = *(const float4*)(bias + n0 + tx * 4);
    bhi = *(const float4*)(bias + n0 + 64 + tx * 4);
  }
#pragma unroll
  for (int i = 0; i < 8; ++i) {
    const int m = m0 + ((i < 4) ? (ty * 4 + i) : (64 + ty * 4 + i - 4));
    float4 lo = make_float4(acc[i][0] + blo.x, acc[i][1] + blo.y,
                            acc[i][2] + blo.z, acc[i][3] + blo.w);
    float4 hi = make_float4(acc[i][4] + bhi.x, acc[i][5] + bhi.y,
                            acc[i][6] + bhi.z, acc[i][7] + bhi.w);
    *(float4*)(C + (size_t)m * ldC + n0 + tx * 4) = lo;
    *(float4*)(C + (size_t)m * ldC + n0 + 64 + tx * 4) = hi;
  }
}

// ---------------- whh repack (R3-verified layout): [d][sl][i4(32)][t(256)][4],
// t = half*128 + r; value = whh[d][gcol(r,sl)][half*128 + i4*4 + c].
__global__ void prep_whh(const float* __restrict__ whh1, const float* __restrict__ whh2,
                         float* __restrict__ o1, float* __restrict__ o2) {
  int idx0 = blockIdx.x * 256 + threadIdx.x;       // 2 * 524288
  int layer = idx0 >> 19;
  int idx = idx0 & 524287;
  const float* whh = layer ? whh2 : whh1;
  float* out = layer ? o2 : o1;
  int c    = idx & 3;
  int t    = (idx >> 2) & 255;
  int i4   = (idx >> 10) & 31;
  int sl   = (idx >> 15) & 7;
  int d    = idx >> 18;
  int r    = t & 127;
  int half = t >> 7;
  int g = (r >> 5) * 256 + sl * 32 + (r & 31);
  int k = half * 128 + i4 * 4 + c;
  out[idx] = whh[(size_t)(d * GG + g) * HH + k];
}

// ---------------- LSTM recurrence — EXACT R3 structure (256 thr, per-thread
// 2-word polls, k-split w[128], p_lds combine, tid<64 epilogue, att-in-rec).
// R5 isolated edits on the latency path only:
//  (1) raw s_barrier + lgkmcnt(0) + sched_barrier(0) instead of __syncthreads:
//      hist stores / xp loads / h atomic store stay in flight across barriers
//      (no per-step vmcnt(0) drain; pattern validated race-free in R4 run)
//  (2) xp prefetched one step ahead (xn regs, issued post-detect); aw loaded
//      into regs post-detect BEFORE xn issue (vmcnt FIFO: att use after matvec
//      doesn't drain the HBM prefetch), consumed after matvec
//  (3) hot spin (no s_sleep) — poll period = pure L2/L3 RT
__launch_bounds__(256, 1)
__global__ void rec_kernel(const float* __restrict__ Xp, const float* __restrict__ whh_p,
                           float* __restrict__ hist, u64* __restrict__ hx,
                           const float* __restrict__ aw, const float* __restrict__ sentW,
                           int useAtt) {
  __shared__ float h_lds[512];       // [c*256 + k]
  __shared__ float p_lds[512];       // [(half*128 + r)*2 + c]
  const int tid = threadIdx.x;
  const int bid = blockIdx.x;
  const int sl = bid >> 5;
  const int db = bid & 31;
  const int d = db & 1;
  const int bg = db >> 1;
  const int r = tid & 127;           // gate row 0..127 (gate*32+j)
  const int half = tid >> 7;         // k-half
  // -------- register-resident whh half-row (w[128]/thread, ~180 VGPR, no spill)
  const float* wp = whh_p + (size_t)(d * 8 + sl) * 32768;
  float w[128];
#pragma unroll
  for (int i4 = 0; i4 < 32; ++i4) {
    const float4 v = *(const float4*)&wp[(size_t)(i4 * 256 + tid) * 4];
    w[i4 * 4 + 0] = v.x; w[i4 * 4 + 1] = v.y;
    w[i4 * 4 + 2] = v.z; w[i4 * 4 + 3] = v.w;
  }
  const float* XpD = Xp + (size_t)d * MM * GG;
  const int gcol = (r >> 5) * 256 + sl * 32 + (r & 31);
  const int jj = tid & 31, cc = tid >> 5;        // producer epilogue mapping (tid<64)
  const int histMine = ((r >> 4) == sl);         // my 2 polled words in my hist slice
  float creg = 0.f;                              // LSTM cell state (valid tid<64)
  // register-cached sentW columns; rank-16 att split by k-half (8 terms each)
  float swA[8], swB[8];
  if (useAtt) {
    const float* swp = sentW + ((size_t)d * 512 + (size_t)(bg * 2) * 16) * 1024 + gcol;
#pragma unroll
    for (int n = 0; n < 8; ++n) {
      swA[n] = swp[(size_t)(half * 8 + n) * 1024];
      swB[n] = swp[(size_t)(16 + half * 8 + n) * 1024];
    }
  }
  // group base: hx[slot][d][bg][512]
  u64* grp[2] = { hx + ((size_t)(0 * 2 + d) * 16 + bg) * 512,
                  hx + ((size_t)(1 * 2 + d) * 16 + bg) * 512 };
  // prologue: xp prefetch for step 0 (half 0 owns the xp add)
  float xn0 = 0.f, xn1 = 0.f;
  if (half == 0) {
    const int s0 = d ? (SS - 1) : 0;
    const int m00 = s0 * BB + bg * 2;
    xn0 = XpD[(size_t)m00 * GG + gcol];
    xn1 = XpD[(size_t)(m00 + 1) * GG + gcol];
  }
#pragma unroll 1
  for (int t = 0; t < SS; ++t) {
    float x0 = xn0, x1 = xn1;        // xp for THIS step (prefetched last step)
    // ---- per-thread barrier-free HOT spin on my 2 tagged words ----
    u64 w0, w1;
    {
      u64* base = grp[t & 1] + tid * 2;
      do {
        w0 = __hip_atomic_load(base + 0, __ATOMIC_RELAXED, __HIP_MEMORY_SCOPE_AGENT);
        w1 = __hip_atomic_load(base + 1, __ATOMIC_RELAXED, __HIP_MEMORY_SCOPE_AGENT);
      } while (((u32)(w0 >> 32) != (u32)t) | ((u32)(w1 >> 32) != (u32)t));
    }
    // aw loads for current step — issued FIRST (vmcnt FIFO), consumed post-matvec
    const int s = d ? (SS - 1 - t) : t;
    const int m0 = s * BB + bg * 2;
    float av0[8], av1[8];
    if (useAtt) {
      const float* a0 = aw + (size_t)m0 * 16 + half * 8;
#pragma unroll
      for (int n = 0; n < 8; ++n) { av0[n] = a0[n]; av1[n] = a0[16 + n]; }
    }
    // xp prefetch for t+1 — issued AFTER aw; drains only at next step's use
    {
      const int tn = (t + 1 < SS) ? (t + 1) : (SS - 1);
      const int sn = d ? (SS - 1 - tn) : tn;
      const int m0n = sn * BB + bg * 2;
      if (half == 0) {
        xn0 = XpD[(size_t)m0n * GG + gcol];
        xn1 = XpD[(size_t)(m0n + 1) * GG + gcol];
      }
    }
    *(float2*)&h_lds[tid * 2] = make_float2(__uint_as_float((u32)w0),
                                            __uint_as_float((u32)w1));
    // distributed hist write for step t-1 (stays in flight past the raw barrier)
    if (histMine && t > 0) {
      const int sp = d ? (SS - t) : (t - 1);
      *(float2*)&hist[(size_t)(sp * BB + bg * 2 + half) * 512 + d * 256 + r * 2] =
          make_float2(__uint_as_float((u32)w0), __uint_as_float((u32)w1));
    }
    // ---- barrier (b): h_lds ready. Raw: globals NOT drained. ----
    asm volatile("s_waitcnt lgkmcnt(0)" ::: "memory");
    __builtin_amdgcn_s_barrier();
    __builtin_amdgcn_sched_barrier(0);
    {
      // matvec: 4 independent accumulator chains; w from regs, h broadcast LDS
      const int kb = half * 128;
      float p0a = 0.f, p0b = 0.f, p1a = 0.f, p1b = 0.f;
#pragma unroll
      for (int k8 = 0; k8 < 16; ++k8) {
        const float4 h0a = *(const float4*)&h_lds[kb + k8 * 8];
        const float4 h0b = *(const float4*)&h_lds[kb + k8 * 8 + 4];
        const float4 h1a = *(const float4*)&h_lds[256 + kb + k8 * 8];
        const float4 h1b = *(const float4*)&h_lds[256 + kb + k8 * 8 + 4];
        p0a = fmaf(w[k8*8+0], h0a.x, p0a); p0a = fmaf(w[k8*8+1], h0a.y, p0a);
        p0a = fmaf(w[k8*8+2], h0a.z, p0a); p0a = fmaf(w[k8*8+3], h0a.w, p0a);
        p0b = fmaf(w[k8*8+4], h0b.x, p0b); p0b = fmaf(w[k8*8+5], h0b.y, p0b);
        p0b = fmaf(w[k8*8+6], h0b.z, p0b); p0b = fmaf(w[k8*8+7], h0b.w, p0b);
        p1a = fmaf(w[k8*8+0], h1a.x, p1a); p1a = fmaf(w[k8*8+1], h1a.y, p1a);
        p1a = fmaf(w[k8*8+2], h1a.z, p1a); p1a = fmaf(w[k8*8+3], h1a.w, p1a);
        p1b = fmaf(w[k8*8+4], h1b.x, p1b); p1b = fmaf(w[k8*8+5], h1b.y, p1b);
        p1b = fmaf(w[k8*8+6], h1b.z, p1b); p1b = fmaf(w[k8*8+7], h1b.w, p1b);
      }
      // rank-16 attention add (aw loads issued pre-barrier, latency hidden)
      if (useAtt) {
#pragma unroll
        for (int n = 0; n < 8; ++n) {
          x0 = fmaf(av0[n], swA[n], x0);
          x1 = fmaf(av1[n], swB[n], x1);
        }
      }
      *(float2*)&p_lds[tid * 2] = make_float2(p0a + p0b + x0, p1a + p1b + x1);
    }
    // ---- barrier (c): p_lds ready; fences h_lds reads vs next-step writes ----
    asm volatile("s_waitcnt lgkmcnt(0)" ::: "memory");
    __builtin_amdgcn_s_barrier();
    __builtin_amdgcn_sched_barrier(0);
    if (tid < 64) {    // producer epilogue: combine k-halves, one 8B L3 atomic
      const float iv = p_lds[(jj) * 2 + cc]       + p_lds[(128 + jj) * 2 + cc];
      const float fv = p_lds[(32 + jj) * 2 + cc]  + p_lds[(128 + 32 + jj) * 2 + cc];
      const float gv = p_lds[(64 + jj) * 2 + cc]  + p_lds[(128 + 64 + jj) * 2 + cc];
      const float ov = p_lds[(96 + jj) * 2 + cc]  + p_lds[(128 + 96 + jj) * 2 + cc];
      const float cs = sigm(fv) * creg + sigm(iv) * tanh_fast(gv);
      creg = cs;
      const float hn = sigm(ov) * tanh_fast(cs);
      u64 wv = ((u64)(u32)(t + 1) << 32) | (u64)__float_as_uint(hn);
      __hip_atomic_store(grp[(t + 1) & 1] + cc * 256 + sl * 32 + jj, wv,
                         __ATOMIC_RELAXED, __HIP_MEMORY_SCOPE_AGENT);
    }
  }
  // distributed final flush (tag SS): each participating thread polls its OWN words
  if (histMine) {
    u64* base = grp[SS & 1] + tid * 2;
    u64 w0, w1;
    do {
      w0 = __hip_atomic_load(base + 0, __ATOMIC_RELAXED, __HIP_MEMORY_SCOPE_AGENT);
      w1 = __hip_atomic_load(base + 1, __ATOMIC_RELAXED, __HIP_MEMORY_SCOPE_AGENT);
      if (((u32)(w0 >> 32) == (u32)SS) & ((u32)(w1 >> 32) == (u32)SS)) break;
      __builtin_amdgcn_s_sleep(1);
    } while (true);
    const int sp = d ? 0 : (SS - 1);
    *(float2*)&hist[(size_t)(sp * BB + bg * 2 + half) * 512 + d * 256 + r * 2] =
        make_float2(__uint_as_float((u32)w0), __uint_as_float((u32)w1));
  }
}

// ---------------- aw: scores over NS=16 sentence embs + softmax -> aw[m][16]
__global__ void aw_kernel(const float* __restrict__ wx, const float* __restrict__ sent,
                          float* __restrict__ awout) {
  __shared__ float sl[NSENT * 512];   // 32 KB
  __shared__ float wxr[512];
  __shared__ float parts[256];
  __shared__ float avals[NSENT];
  __shared__ float red0;
  const int tid = threadIdx.x;
  const int b = blockIdx.y;
  const int s0 = blockIdx.x * 32;
  for (int i = tid; i < NSENT * 512; i += 256) sl[i] = sent[(size_t)b * NSENT * 512 + i];
  __syncthreads();
  for (int si = 0; si < 32; ++si) {
    const int m = (s0 + si) * BB + b;
    for (int i = tid; i < 512; i += 256) wxr[i] = wx[(size_t)m * 512 + i];
    __syncthreads();
    const int n = tid >> 4, kp = tid & 15;
    float p = 0.f;
#pragma unroll 8
    for (int f = kp * 32; f < kp * 32 + 32; ++f) p = fmaf(wxr[f], sl[n * 512 + f], p);
    parts[tid] = p;
    __syncthreads();
    if (tid < NSENT) {
      float sc = 0.f;
      for (int qq = 0; qq < 16; ++qq) sc += parts[tid * 16 + qq];
      avals[tid] = sc;
    }
    __syncthreads();
    if (tid == 0) {
      float mx = avals[0];
      for (int qq = 1; qq < NSENT; ++qq) mx = fmaxf(mx, avals[qq]);
      float sm = 0.f;
      for (int qq = 0; qq < NSENT; ++qq) { float e = expf(avals[qq] - mx); avals[qq] = e; sm += e; }
      red0 = 1.f / sm;
    }
    __syncthreads();
    if (tid < NSENT) awout[(size_t)m * 16 + tid] = avals[tid] * red0;
    __syncthreads();
  }
}

// ---------------- feats[m][t] = l2m[m][:] . h2t_w[t][:] + h2t_b[t]; wave per row
__global__ void feats_kernel(const float* __restrict__ l2m, const float* __restrict__ w,
                             const float* __restrict__ bias, float* __restrict__ feats) {
  const int wave = threadIdx.x >> 6, lane = threadIdx.x & 63;
  const int m = blockIdx.x * 4 + wave;
  const float* row = l2m + (size_t)m * 512;
  float rv[8];
#pragma unroll
  for (int i = 0; i < 8; ++i) rv[i] = row[lane + i * 64];
  for (int t = 0; t < TT; ++t) {
    const float* wr = w + t * 512;
    float p = 0.f;
#pragma unroll
    for (int i = 0; i < 8; ++i) p = fmaf(rv[i], wr[lane + i * 64], p);
#pragma unroll
    for (int off = 32; off; off >>= 1) p += __shfl_down(p, off);
    if (lane == 0) feats[(size_t)m * TT + t] = p + bias[t];
  }
}

// ---------------- viterbi per batch; 1 wave, whole DP in LDS
__global__ void viterbi_kernel(const float* __restrict__ feats, const float* __restrict__ trans,
                               int* __restrict__ out) {
  __shared__ float flds[SS * TT];
  __shared__ unsigned char bp[SS * TT];
  __shared__ float tr[TT * TT];
  __shared__ float fv[TT];
  __shared__ float tv[TT];
  __shared__ int pathS[SS];
  const int b = blockIdx.x, tid = threadIdx.x;
  for (int i = tid; i < SS * TT; i += 64) {
    int s = i / TT, t = i - s * TT;
    flds[i] = feats[(size_t)(s * BB + b) * TT + t];
  }
  for (int i = tid; i < TT * TT; i += 64) tr[i] = trans[i];
  if (tid < TT) fv[tid] = (tid == TAG_START) ? 0.f : -10000.f;
  __syncthreads();
  for (int s = 0; s < SS; ++s) {
    float nf = 0.f;
    if (tid < TT) {
      float mx = -1e30f;
      int bj = 0;
#pragma unroll
      for (int jj = 0; jj < TT; ++jj) {
        float v = fv[jj] + tr[tid * TT + jj];
        if (v > mx) { mx = v; bj = jj; }
      }
      nf = mx + flds[s * TT + tid];
      bp[s * TT + tid] = (unsigned char)bj;
    }
    __syncthreads();
    if (tid < TT) fv[tid] = nf;
    __syncthreads();
  }
  if (tid < TT) tv[tid] = fv[tid] + tr[TAG_STOP * TT + tid];
  __syncthreads();
  if (tid == 0) {
    int best = 0;
    float mx = tv[0];
    for (int jj = 1; jj < TT; ++jj)
      if (tv[jj] > mx) { mx = tv[jj]; best = jj; }
    pathS[SS - 1] = best;
    for (int s = SS - 1; s > 0; --s) { best = bp[s * TT + best]; pathS[s - 1] = best; }
  }
  __syncthreads();
  for (int s = tid; s < SS; s += 64) out[b * SS + s] = pathS[s];
}

// ---------------- workspace layout (bytes) — total ~245.6 MB < 256 MB ----------------
#define OFF_XP    ((size_t)0)               // 2*16384*1024*4 = 134217728
#define OFF_WX    ((size_t)134217728)       // 16384*512*4 = 33554432
#define OFF_L2M   ((size_t)167772160)       // 16384*512*4 = 33554432 (X1 aliases here)
#define OFF_WORD  ((size_t)201326592)       // 16384*512*4 = 33554432
#define OFF_WT1   ((size_t)234881024)       // 2097152
#define OFF_WT2   ((size_t)236978176)       // 2097152
#define OFF_FEATS ((size_t)239075328)       // 786432
#define OFF_HX1   ((size_t)239861760)       // 262144
#define OFF_HX2   ((size_t)240123904)       // 262144
#define OFF_SENTW ((size_t)240386048)       // 2*512*1024*4 = 4194304
#define OFF_AW    ((size_t)244580352)       // 16384*16*4 = 1048576

extern "C" void kernel_launch(void* const* d_in, const int* in_sizes, int n_in,
                              void* d_out, int out_size, void* d_ws, size_t ws_size,
                              hipStream_t stream) {
  const int* inputs  = (const int*)d_in[0];
  const float* sent  = (const float*)d_in[1];
  const float* emb   = (const float*)d_in[2];
  const float* l1wih = (const float*)d_in[3];
  const float* l1whh = (const float*)d_in[4];
  const float* l1b   = (const float*)d_in[5];
  const float* l2wih = (const float*)d_in[6];
  const float* l2whh = (const float*)d_in[7];
  const float* l2b   = (const float*)d_in[8];
  const float* attW  = (const float*)d_in[9];
  const float* h2tw  = (const float*)d_in[10];
  const float* h2tb  = (const float*)d_in[11];
  const float* trans = (const float*)d_in[12];
  int* out = (int*)d_out;
  char* ws = (char*)d_ws;

  float* Xp    = (float*)(ws + OFF_XP);
  float* wx    = (float*)(ws + OFF_WX);
  float* l2m   = (float*)(ws + OFF_L2M);
  float* X1    = l2m;    // X1 dead (read only by l1 gemms) before rec2 writes l2m
  float* word  = (float*)(ws + OFF_WORD);
  float* wt1   = (float*)(ws + OFF_WT1);
  float* wt2   = (float*)(ws + OFF_WT2);
  float* feats = (float*)(ws + OFF_FEATS);
  u64* hx1     = (u64*)(ws + OFF_HX1);
  u64* hx2     = (u64*)(ws + OFF_HX2);
  float* sentW = (float*)(ws + OFF_SENTW);
  float* awb   = (float*)(ws + OFF_AW);

  // zero both tagged-h buffers (contiguous 512 KB): tag 0 == "h_{-1}=0 ready"
  (void)hipMemsetAsync(ws + OFF_HX1, 0, 262144 * 2, stream);

  prep_whh<<<4096, 256, 0, stream>>>(l1whh, l2whh, wt1, wt2);
  // sentW[d][b*16+n][g] = sent[b][n][:512] . l2wih[d][g][512:1024]
  gemm_nt<<<dim3(8, 4, 2), 256, 0, stream>>>(sent, l2wih + 512, nullptr, sentW,
                                             512, 512, GG, 1024,
                                             (size_t)GG * GG, (size_t)512 * 1024);
  embed_kernel<<<MM, 64, 0, stream>>>(inputs, emb, X1);
  gemm_nt<<<dim3(8, 128, 2), 256, 0, stream>>>(X1, l1wih, l1b, Xp,
                                               DD, DD, DD, GG,
                                               (size_t)GG * DD, (size_t)MM * GG);
  rec_kernel<<<256, 256, 0, stream>>>(Xp, wt1, word, hx1, nullptr, nullptr, 0);
  // wx = word @ attW^T
  gemm_nt<<<dim3(4, 128, 1), 256, 0, stream>>>(word, attW, nullptr, wx,
                                               512, 512, 512, 512, 0, 0);
  aw_kernel<<<dim3(16, 32), 256, 0, stream>>>(wx, sent, awb);
  // Xp2 = wx @ l2wih[:, :512]^T + bias   (K halved; attention half folded into rec2)
  gemm_nt<<<dim3(8, 128, 2), 256, 0, stream>>>(wx, l2wih, l2b, Xp,
                                               512, 512, GG, GG,
                                               (size_t)GG * GG, (size_t)MM * GG);
  rec_kernel<<<256, 256, 0, stream>>>(Xp, wt2, l2m, hx2, awb, sentW, 1);
  feats_kernel<<<MM / 4, 256, 0, stream>>>(l2m, h2tw, h2tb, feats);
  viterbi_kernel<<<BB, 64, 0, stream>>>(feats, trans, out);
}

// Round 6
// 4074.673 us; speedup vs baseline: 2.0708x; 1.7126x over previous
//
#include <hip/hip_runtime.h>
#include <hip/hip_bf16.h>

// Problem constants
#define BB 32
#define SS 512
#define DD 256
#define HH 256
#define GG 1024          // 4*H
#define MM (SS*BB)       // 16384 rows, m = s*32 + b
#define NSENT 16
#define TT 12
#define TAG_START 10
#define TAG_STOP 11

typedef unsigned long long u64;
typedef unsigned int u32;

__device__ __forceinline__ float sigm(float x) {
  x = fminf(fmaxf(x, -15.f), 15.f);
  return 1.f / (1.f + __expf(-x));
}
__device__ __forceinline__ float tanh_fast(float x) {
  x = fminf(fmaxf(x, -15.f), 15.f);
  float e = __expf(2.f * x);
  return (e - 1.f) / (e + 1.f);
}

// ---------------- embed gather: X1[m][d] = embed[inputs[b][s]][d], m = s*32+b
__global__ void embed_kernel(const int* __restrict__ toks, const float* __restrict__ emb,
                             float* __restrict__ X1) {
  int m = blockIdx.x;
  int s = m >> 5, b = m & 31;
  int tok = toks[b * SS + s];
  ((float4*)(X1 + (size_t)m * DD))[threadIdx.x] =
      ((const float4*)(emb + (size_t)tok * DD))[threadIdx.x];
}

// ---------------- fp32 NT GEMM (R9-verified core + z-batching):
// C[M,N] = A[M,K](lda) @ W[N,K](ldw)^T + bias.  128x128 tile, 8x8/thread.
// blockIdx.z selects direction: W += z*wz, C += z*cz, bias += z*GG.
__launch_bounds__(256)
__global__ void gemm_nt(const float* __restrict__ A, const float* __restrict__ W_,
                        const float* __restrict__ bias_, float* __restrict__ C_,
                        int K, int lda, int ldw, int ldC, size_t wz, size_t cz) {
  __shared__ float As[16 * 132];
  __shared__ float Ws[16 * 132];
  const float* W = W_ + (size_t)blockIdx.z * wz;
  const float* bias = bias_ ? bias_ + (size_t)blockIdx.z * GG : nullptr;
  float* C = C_ + (size_t)blockIdx.z * cz;
  const int tid = threadIdx.x;
  const int n0 = blockIdx.x * 128, m0 = blockIdx.y * 128;
  const int row = tid & 127, half = tid >> 7;    // staging: 128 rows x 2 k-halves
  const int tx = tid & 15, ty = tid >> 4;        // compute: 16x16 thread grid
  float acc[8][8] = {};
  const float* Arow = A + (size_t)(m0 + row) * lda;
  const float* Wrow = W + (size_t)(n0 + row) * ldw;
  for (int kk = 0; kk < K; kk += 16) {
    const int kb = half * 8;
    float4 a0 = *(const float4*)(Arow + kk + kb);
    float4 a1 = *(const float4*)(Arow + kk + kb + 4);
    float4 w0 = *(const float4*)(Wrow + kk + kb);
    float4 w1 = *(const float4*)(Wrow + kk + kb + 4);
    As[(kb + 0) * 132 + row] = a0.x; As[(kb + 1) * 132 + row] = a0.y;
    As[(kb + 2) * 132 + row] = a0.z; As[(kb + 3) * 132 + row] = a0.w;
    As[(kb + 4) * 132 + row] = a1.x; As[(kb + 5) * 132 + row] = a1.y;
    As[(kb + 6) * 132 + row] = a1.z; As[(kb + 7) * 132 + row] = a1.w;
    Ws[(kb + 0) * 132 + row] = w0.x; Ws[(kb + 1) * 132 + row] = w0.y;
    Ws[(kb + 2) * 132 + row] = w0.z; Ws[(kb + 3) * 132 + row] = w0.w;
    Ws[(kb + 4) * 132 + row] = w1.x; Ws[(kb + 5) * 132 + row] = w1.y;
    Ws[(kb + 6) * 132 + row] = w1.z; Ws[(kb + 7) * 132 + row] = w1.w;
    __syncthreads();
#pragma unroll
    for (int kl = 0; kl < 16; ++kl) {
      const float4 alo = *(const float4*)&As[kl * 132 + ty * 4];
      const float4 ahi = *(const float4*)&As[kl * 132 + 64 + ty * 4];
      const float4 wlo = *(const float4*)&Ws[kl * 132 + tx * 4];
      const float4 whi = *(const float4*)&Ws[kl * 132 + 64 + tx * 4];
      const float am[8] = {alo.x, alo.y, alo.z, alo.w, ahi.x, ahi.y, ahi.z, ahi.w};
      const float wm[8] = {wlo.x, wlo.y, wlo.z, wlo.w, whi.x, whi.y, whi.z, whi.w};
#pragma unroll
      for (int i = 0; i < 8; ++i)
#pragma unroll
        for (int j = 0; j < 8; ++j) acc[i][j] = fmaf(am[i], wm[j], acc[i][j]);
    }
    __syncthreads();
  }
  float4 blo = make_float4(0.f, 0.f, 0.f, 0.f), bhi = blo;
  if (bias) {
    blo = *(const float4*)(bias + n0 + tx * 4);
    bhi = *(const float4*)(bias + n0 + 64 + tx * 4);
  }
#pragma unroll
  for (int i = 0; i < 8; ++i) {
    const int m = m0 + ((i < 4) ? (ty * 4 + i) : (64 + ty * 4 + i - 4));
    float4 lo = make_float4(acc[i][0] + blo.x, acc[i][1] + blo.y,
                            acc[i][2] + blo.z, acc[i][3] + blo.w);
    float4 hi = make_float4(acc[i][4] + bhi.x, acc[i][5] + bhi.y,
                            acc[i][6] + bhi.z, acc[i][7] + bhi.w);
    *(float4*)(C + (size_t)m * ldC + n0 + tx * 4) = lo;
    *(float4*)(C + (size_t)m * ldC + n0 + 64 + tx * 4) = hi;
  }
}

// ---------------- whh repack (R3-verified layout): [d][sl][i4(32)][t(256)][4],
// t = half*128 + r; value = whh[d][gcol(r,sl)][half*128 + i4*4 + c].
__global__ void prep_whh(const float* __restrict__ whh1, const float* __restrict__ whh2,
                         float* __restrict__ o1, float* __restrict__ o2) {
  int idx0 = blockIdx.x * 256 + threadIdx.x;       // 2 * 524288
  int layer = idx0 >> 19;
  int idx = idx0 & 524287;
  const float* whh = layer ? whh2 : whh1;
  float* out = layer ? o2 : o1;
  int c    = idx & 3;
  int t    = (idx >> 2) & 255;
  int i4   = (idx >> 10) & 31;
  int sl   = (idx >> 15) & 7;
  int d    = idx >> 18;
  int r    = t & 127;
  int half = t >> 7;
  int g = (r >> 5) * 256 + sl * 32 + (r & 31);
  int k = half * 128 + i4 * 4 + c;
  out[idx] = whh[(size_t)(d * GG + g) * HH + k];
}

// ---------------- LSTM recurrence — EXACT R3 structure (3931us champion:
// 256 thr, per-thread 2-word polls w/ s_sleep, k-split w[128] in VGPRs,
// p_lds combine, tid<64 epilogue, att folded into rec2, __syncthreads).
// R6 single edit: hist store MOVED from pre-barrier-(b) to post-barrier-(c).
// Rationale: __syncthreads drains vmcnt(0); with the store issued right
// before (b) its ack (~300-700cy) sat on every step's critical path. Issued
// after (c), it drains at the NEXT step's (b) — after the ~2000cy spin —
// for free. Zero new constructs; +2 VGPR worst case (w0/w1 live thru matvec).
__launch_bounds__(256, 1)
__global__ void rec_kernel(const float* __restrict__ Xp, const float* __restrict__ whh_p,
                           float* __restrict__ hist, u64* __restrict__ hx,
                           const float* __restrict__ aw, const float* __restrict__ sentW,
                           int useAtt) {
  __shared__ float h_lds[512];       // [c*256 + k]
  __shared__ float p_lds[512];       // [(half*128 + r)*2 + c]
  const int tid = threadIdx.x;
  const int bid = blockIdx.x;
  const int sl = bid >> 5;
  const int db = bid & 31;
  const int d = db & 1;
  const int bg = db >> 1;
  const int r = tid & 127;           // gate row 0..127 (gate*32+j)
  const int half = tid >> 7;         // k-half: k in [half*128, half*128+128)
  // -------- register-resident whh half-row (w[128]/thread; ~166 VGPR, no spill)
  const float* wp = whh_p + (size_t)(d * 8 + sl) * 32768;
  float w[128];
#pragma unroll
  for (int i4 = 0; i4 < 32; ++i4) {
    const float4 v = *(const float4*)&wp[(size_t)(i4 * 256 + tid) * 4];
    w[i4 * 4 + 0] = v.x; w[i4 * 4 + 1] = v.y;
    w[i4 * 4 + 2] = v.z; w[i4 * 4 + 3] = v.w;
  }
  const float* XpD = Xp + (size_t)d * MM * GG;
  const int gcol = (r >> 5) * 256 + sl * 32 + (r & 31);
  const int jj = tid & 31, cc = tid >> 5;        // producer epilogue mapping (tid<64)
  const int histMine = ((r >> 4) == sl);         // my 2 polled words in my hist slice
  float creg = 0.f;                              // LSTM cell state (valid tid<64)
  // register-cached sentW columns; rank-16 att split by k-half (8 terms each)
  float swA[8], swB[8];
  if (useAtt) {
    const float* swp = sentW + ((size_t)d * 512 + (size_t)(bg * 2) * 16) * 1024 + gcol;
#pragma unroll
    for (int n = 0; n < 8; ++n) {
      swA[n] = swp[(size_t)(half * 8 + n) * 1024];
      swB[n] = swp[(size_t)(16 + half * 8 + n) * 1024];
    }
  }
  // group base: hx[slot][d][bg][512]
  u64* grp[2] = { hx + ((size_t)(0 * 2 + d) * 16 + bg) * 512,
                  hx + ((size_t)(1 * 2 + d) * 16 + bg) * 512 };
#pragma unroll 1
  for (int t = 0; t < SS; ++t) {
    const int s = d ? (SS - 1 - t) : t;
    // xp loads + aw loads issued before the spin (latency hidden under spin)
    const int m0 = s * BB + bg * 2;
    float x0 = 0.f, x1 = 0.f;
    if (half == 0) {
      x0 = XpD[(size_t)m0 * GG + gcol];
      x1 = XpD[(size_t)(m0 + 1) * GG + gcol];
    }
    if (useAtt) {
      const float* a0 = aw + (size_t)m0 * 16;     // rows m0, m0+1 contiguous
#pragma unroll
      for (int n = 0; n < 8; ++n) {
        x0 = fmaf(a0[half * 8 + n], swA[n], x0);
        x1 = fmaf(a0[16 + half * 8 + n], swB[n], x1);
      }
    }
    // ---- per-thread barrier-free spin on my 2 tagged words ----
    u64 w0, w1;
    {
      u64* base = grp[t & 1] + tid * 2;
      w0 = __hip_atomic_load(base + 0, __ATOMIC_RELAXED, __HIP_MEMORY_SCOPE_AGENT);
      w1 = __hip_atomic_load(base + 1, __ATOMIC_RELAXED, __HIP_MEMORY_SCOPE_AGENT);
      while (((u32)(w0 >> 32) != (u32)t) | ((u32)(w1 >> 32) != (u32)t)) {
        __builtin_amdgcn_s_sleep(1);
        w0 = __hip_atomic_load(base + 0, __ATOMIC_RELAXED, __HIP_MEMORY_SCOPE_AGENT);
        w1 = __hip_atomic_load(base + 1, __ATOMIC_RELAXED, __HIP_MEMORY_SCOPE_AGENT);
      }
    }
    *(float2*)&h_lds[tid * 2] = make_float2(__uint_as_float((u32)w0),
                                            __uint_as_float((u32)w1));
    __syncthreads();   // (b) h_lds complete (no outstanding store -> free drain)
    {
      // matvec: 4 independent accumulator chains; w from regs, h broadcast LDS
      const int kb = half * 128;
      float p0a = 0.f, p0b = 0.f, p1a = 0.f, p1b = 0.f;
#pragma unroll
      for (int k8 = 0; k8 < 16; ++k8) {
        const float4 h0a = *(const float4*)&h_lds[kb + k8 * 8];
        const float4 h0b = *(const float4*)&h_lds[kb + k8 * 8 + 4];
        const float4 h1a = *(const float4*)&h_lds[256 + kb + k8 * 8];
        const float4 h1b = *(const float4*)&h_lds[256 + kb + k8 * 8 + 4];
        p0a = fmaf(w[k8*8+0], h0a.x, p0a); p0a = fmaf(w[k8*8+1], h0a.y, p0a);
        p0a = fmaf(w[k8*8+2], h0a.z, p0a); p0a = fmaf(w[k8*8+3], h0a.w, p0a);
        p0b = fmaf(w[k8*8+4], h0b.x, p0b); p0b = fmaf(w[k8*8+5], h0b.y, p0b);
        p0b = fmaf(w[k8*8+6], h0b.z, p0b); p0b = fmaf(w[k8*8+7], h0b.w, p0b);
        p1a = fmaf(w[k8*8+0], h1a.x, p1a); p1a = fmaf(w[k8*8+1], h1a.y, p1a);
        p1a = fmaf(w[k8*8+2], h1a.z, p1a); p1a = fmaf(w[k8*8+3], h1a.w, p1a);
        p1b = fmaf(w[k8*8+4], h1b.x, p1b); p1b = fmaf(w[k8*8+5], h1b.y, p1b);
        p1b = fmaf(w[k8*8+6], h1b.z, p1b); p1b = fmaf(w[k8*8+7], h1b.w, p1b);
      }
      *(float2*)&p_lds[tid * 2] = make_float2(p0a + p0b + x0, p1a + p1b + x1);
    }
    __syncthreads();   // (c) p_lds ready; fences h_lds reads vs next-step writes
    if (tid < 64) {    // producer epilogue: combine k-halves, one 8B L3 atomic
      const float iv = p_lds[(jj) * 2 + cc]       + p_lds[(128 + jj) * 2 + cc];
      const float fv = p_lds[(32 + jj) * 2 + cc]  + p_lds[(128 + 32 + jj) * 2 + cc];
      const float gv = p_lds[(64 + jj) * 2 + cc]  + p_lds[(128 + 64 + jj) * 2 + cc];
      const float ov = p_lds[(96 + jj) * 2 + cc]  + p_lds[(128 + 96 + jj) * 2 + cc];
      const float cs = sigm(fv) * creg + sigm(iv) * tanh_fast(gv);
      creg = cs;
      const float hn = sigm(ov) * tanh_fast(cs);
      u64 wv = ((u64)(u32)(t + 1) << 32) | (u64)__float_as_uint(hn);
      __hip_atomic_store(grp[(t + 1) & 1] + cc * 256 + sl * 32 + jj, wv,
                         __ATOMIC_RELAXED, __HIP_MEMORY_SCOPE_AGENT);
    }
    // distributed hist write for step t-1 — moved POST-(c): drains at next
    // step's (b) after the long spin, i.e. off the critical path
    if (histMine && t > 0) {
      const int sp = d ? (SS - t) : (t - 1);
      *(float2*)&hist[(size_t)(sp * BB + bg * 2 + half) * 512 + d * 256 + r * 2] =
          make_float2(__uint_as_float((u32)w0), __uint_as_float((u32)w1));
    }
  }
  // distributed final flush (tag SS): each participating thread polls its OWN words
  if (histMine) {
    u64* base = grp[SS & 1] + tid * 2;
    u64 w0, w1;
    do {
      w0 = __hip_atomic_load(base + 0, __ATOMIC_RELAXED, __HIP_MEMORY_SCOPE_AGENT);
      w1 = __hip_atomic_load(base + 1, __ATOMIC_RELAXED, __HIP_MEMORY_SCOPE_AGENT);
      if (((u32)(w0 >> 32) == (u32)SS) & ((u32)(w1 >> 32) == (u32)SS)) break;
      __builtin_amdgcn_s_sleep(1);
    } while (true);
    const int sp = d ? 0 : (SS - 1);
    *(float2*)&hist[(size_t)(sp * BB + bg * 2 + half) * 512 + d * 256 + r * 2] =
        make_float2(__uint_as_float((u32)w0), __uint_as_float((u32)w1));
  }
}

// ---------------- aw: scores over NS=16 sentence embs + softmax -> aw[m][16]
__global__ void aw_kernel(const float* __restrict__ wx, const float* __restrict__ sent,
                          float* __restrict__ awout) {
  __shared__ float sl[NSENT * 512];   // 32 KB
  __shared__ float wxr[512];
  __shared__ float parts[256];
  __shared__ float avals[NSENT];
  __shared__ float red0;
  const int tid = threadIdx.x;
  const int b = blockIdx.y;
  const int s0 = blockIdx.x * 32;
  for (int i = tid; i < NSENT * 512; i += 256) sl[i] = sent[(size_t)b * NSENT * 512 + i];
  __syncthreads();
  for (int si = 0; si < 32; ++si) {
    const int m = (s0 + si) * BB + b;
    for (int i = tid; i < 512; i += 256) wxr[i] = wx[(size_t)m * 512 + i];
    __syncthreads();
    const int n = tid >> 4, kp = tid & 15;
    float p = 0.f;
#pragma unroll 8
    for (int f = kp * 32; f < kp * 32 + 32; ++f) p = fmaf(wxr[f], sl[n * 512 + f], p);
    parts[tid] = p;
    __syncthreads();
    if (tid < NSENT) {
      float sc = 0.f;
      for (int qq = 0; qq < 16; ++qq) sc += parts[tid * 16 + qq];
      avals[tid] = sc;
    }
    __syncthreads();
    if (tid == 0) {
      float mx = avals[0];
      for (int qq = 1; qq < NSENT; ++qq) mx = fmaxf(mx, avals[qq]);
      float sm = 0.f;
      for (int qq = 0; qq < NSENT; ++qq) { float e = expf(avals[qq] - mx); avals[qq] = e; sm += e; }
      red0 = 1.f / sm;
    }
    __syncthreads();
    if (tid < NSENT) awout[(size_t)m * 16 + tid] = avals[tid] * red0;
    __syncthreads();
  }
}

// ---------------- feats[m][t] = l2m[m][:] . h2t_w[t][:] + h2t_b[t]; wave per row
__global__ void feats_kernel(const float* __restrict__ l2m, const float* __restrict__ w,
                             const float* __restrict__ bias, float* __restrict__ feats) {
  const int wave = threadIdx.x >> 6, lane = threadIdx.x & 63;
  const int m = blockIdx.x * 4 + wave;
  const float* row = l2m + (size_t)m * 512;
  float rv[8];
#pragma unroll
  for (int i = 0; i < 8; ++i) rv[i] = row[lane + i * 64];
  for (int t = 0; t < TT; ++t) {
    const float* wr = w + t * 512;
    float p = 0.f;
#pragma unroll
    for (int i = 0; i < 8; ++i) p = fmaf(rv[i], wr[lane + i * 64], p);
#pragma unroll
    for (int off = 32; off; off >>= 1) p += __shfl_down(p, off);
    if (lane == 0) feats[(size_t)m * TT + t] = p + bias[t];
  }
}

// ---------------- viterbi per batch; 1 wave, whole DP in LDS
__global__ void viterbi_kernel(const float* __restrict__ feats, const float* __restrict__ trans,
                               int* __restrict__ out) {
  __shared__ float flds[SS * TT];
  __shared__ unsigned char bp[SS * TT];
  __shared__ float tr[TT * TT];
  __shared__ float fv[TT];
  __shared__ float tv[TT];
  __shared__ int pathS[SS];
  const int b = blockIdx.x, tid = threadIdx.x;
  for (int i = tid; i < SS * TT; i += 64) {
    int s = i / TT, t = i - s * TT;
    flds[i] = feats[(size_t)(s * BB + b) * TT + t];
  }
  for (int i = tid; i < TT * TT; i += 64) tr[i] = trans[i];
  if (tid < TT) fv[tid] = (tid == TAG_START) ? 0.f : -10000.f;
  __syncthreads();
  for (int s = 0; s < SS; ++s) {
    float nf = 0.f;
    if (tid < TT) {
      float mx = -1e30f;
      int bj = 0;
#pragma unroll
      for (int jj = 0; jj < TT; ++jj) {
        float v = fv[jj] + tr[tid * TT + jj];
        if (v > mx) { mx = v; bj = jj; }
      }
      nf = mx + flds[s * TT + tid];
      bp[s * TT + tid] = (unsigned char)bj;
    }
    __syncthreads();
    if (tid < TT) fv[tid] = nf;
    __syncthreads();
  }
  if (tid < TT) tv[tid] = fv[tid] + tr[TAG_STOP * TT + tid];
  __syncthreads();
  if (tid == 0) {
    int best = 0;
    float mx = tv[0];
    for (int jj = 1; jj < TT; ++jj)
      if (tv[jj] > mx) { mx = tv[jj]; best = jj; }
    pathS[SS - 1] = best;
    for (int s = SS - 1; s > 0; --s) { best = bp[s * TT + best]; pathS[s - 1] = best; }
  }
  __syncthreads();
  for (int s = tid; s < SS; s += 64) out[b * SS + s] = pathS[s];
}

// ---------------- workspace layout (bytes) — total ~245.6 MB < 256 MB ----------------
#define OFF_XP    ((size_t)0)               // 2*16384*1024*4 = 134217728
#define OFF_WX    ((size_t)134217728)       // 16384*512*4 = 33554432
#define OFF_L2M   ((size_t)167772160)       // 16384*512*4 = 33554432 (X1 aliases here)
#define OFF_WORD  ((size_t)201326592)       // 16384*512*4 = 33554432
#define OFF_WT1   ((size_t)234881024)       // 2097152
#define OFF_WT2   ((size_t)236978176)       // 2097152
#define OFF_FEATS ((size_t)239075328)       // 786432
#define OFF_HX1   ((size_t)239861760)       // 262144
#define OFF_HX2   ((size_t)240123904)       // 262144
#define OFF_SENTW ((size_t)240386048)       // 2*512*1024*4 = 4194304
#define OFF_AW    ((size_t)244580352)       // 16384*16*4 = 1048576

extern "C" void kernel_launch(void* const* d_in, const int* in_sizes, int n_in,
                              void* d_out, int out_size, void* d_ws, size_t ws_size,
                              hipStream_t stream) {
  const int* inputs  = (const int*)d_in[0];
  const float* sent  = (const float*)d_in[1];
  const float* emb   = (const float*)d_in[2];
  const float* l1wih = (const float*)d_in[3];
  const float* l1whh = (const float*)d_in[4];
  const float* l1b   = (const float*)d_in[5];
  const float* l2wih = (const float*)d_in[6];
  const float* l2whh = (const float*)d_in[7];
  const float* l2b   = (const float*)d_in[8];
  const float* attW  = (const float*)d_in[9];
  const float* h2tw  = (const float*)d_in[10];
  const float* h2tb  = (const float*)d_in[11];
  const float* trans = (const float*)d_in[12];
  int* out = (int*)d_out;
  char* ws = (char*)d_ws;

  float* Xp    = (float*)(ws + OFF_XP);
  float* wx    = (float*)(ws + OFF_WX);
  float* l2m   = (float*)(ws + OFF_L2M);
  float* X1    = l2m;    // X1 dead (read only by l1 gemms) before rec2 writes l2m
  float* word  = (float*)(ws + OFF_WORD);
  float* wt1   = (float*)(ws + OFF_WT1);
  float* wt2   = (float*)(ws + OFF_WT2);
  float* feats = (float*)(ws + OFF_FEATS);
  u64* hx1     = (u64*)(ws + OFF_HX1);
  u64* hx2     = (u64*)(ws + OFF_HX2);
  float* sentW = (float*)(ws + OFF_SENTW);
  float* awb   = (float*)(ws + OFF_AW);

  // zero both tagged-h buffers (contiguous 512 KB): tag 0 == "h_{-1}=0 ready"
  (void)hipMemsetAsync(ws + OFF_HX1, 0, 262144 * 2, stream);

  prep_whh<<<4096, 256, 0, stream>>>(l1whh, l2whh, wt1, wt2);
  // sentW[d][b*16+n][g] = sent[b][n][:512] . l2wih[d][g][512:1024]
  gemm_nt<<<dim3(8, 4, 2), 256, 0, stream>>>(sent, l2wih + 512, nullptr, sentW,
                                             512, 512, GG, 1024,
                                             (size_t)GG * GG, (size_t)512 * 1024);
  embed_kernel<<<MM, 64, 0, stream>>>(inputs, emb, X1);
  gemm_nt<<<dim3(8, 128, 2), 256, 0, stream>>>(X1, l1wih, l1b, Xp,
                                               DD, DD, DD, GG,
                                               (size_t)GG * DD, (size_t)MM * GG);
  rec_kernel<<<256, 256, 0, stream>>>(Xp, wt1, word, hx1, nullptr, nullptr, 0);
  // wx = word @ attW^T
  gemm_nt<<<dim3(4, 128, 1), 256, 0, stream>>>(word, attW, nullptr, wx,
                                               512, 512, 512, 512, 0, 0);
  aw_kernel<<<dim3(16, 32), 256, 0, stream>>>(wx, sent, awb);
  // Xp2 = wx @ l2wih[:, :512]^T + bias   (K halved; attention half folded into rec2)
  gemm_nt<<<dim3(8, 128, 2), 256, 0, stream>>>(wx, l2wih, l2b, Xp,
                                               512, 512, GG, GG,
                                               (size_t)GG * GG, (size_t)MM * GG);
  rec_kernel<<<256, 256, 0, stream>>>(Xp, wt2, l2m, hx2, awb, sentW, 1);
  feats_kernel<<<MM / 4, 256, 0, stream>>>(l2m, h2tw, h2tb, feats);
  viterbi_kernel<<<BB, 64, 0, stream>>>(feats, trans, out);
}